// Round 6
// baseline (189.108 us; speedup 1.0000x reference)
//
#include <hip/hip_runtime.h>
#include <hip/hip_bf16.h>
#include <stdint.h>

typedef uint32_t u32;
typedef uint64_t u64;
typedef __bf16 bf16x8 __attribute__((ext_vector_type(8)));
typedef float f32x4 __attribute__((ext_vector_type(4)));
typedef u32 u32x4 __attribute__((ext_vector_type(4)));

#define NB 8
#define NN 2048
#define DIN 256
#define DOUT 256
#define NR 4
#define KTOT (NN * NR)  // 8192

// ws layout
#define XW_BYTES   (NB * DOUT * KTOT * 2)          // 33,554,432
#define PART_BYTES (NB * NN * DOUT * 4)            // 16,777,216

__device__ __forceinline__ ushort f2bf(float f) {
  union { float f; u32 u; } c; c.f = f;
  return (ushort)((c.u + 0x7FFFu + ((c.u >> 16) & 1u)) >> 16);
}

__device__ __forceinline__ void gload_lds16(const void* g, void* l) {
  __builtin_amdgcn_global_load_lds(
      (const __attribute__((address_space(1))) u32*)g,
      (__attribute__((address_space(3))) u32*)l, 16, 0, 0);
}

// one-hot A fragment: 8 bf16 covering k = {m0 r0..3, m0+1 r0..3}
__device__ __forceinline__ bf16x8 onehot8(int v0, int v1) {
  u32 sa = ((u32)(v0 - 1) & 3u) * 16u;
  u32 sb = ((u32)(v1 - 1) & 3u) * 16u;
  u64 ha = v0 ? (0x3F80ull << sa) : 0ull;
  u64 hb = v1 ? (0x3F80ull << sb) : 0ull;
  union { u32x4 u; bf16x8 b; } c;
  c.u = (u32x4){(u32)ha, (u32)(ha >> 32), (u32)hb, (u32)(hb >> 32)};
  return c.b;
}

// ---------------- kernel 0: wT[r][o][d] = bf16(w[r][d][o]) ----------------
__global__ void k0_wT(const float* __restrict__ w, ushort* __restrict__ wT) {
  int i = blockIdx.x * 256 + threadIdx.x;   // 262144 total
  int o = i & 255, d = (i >> 8) & 255, r = i >> 16;
  wT[(r * DOUT + o) * DIN + d] = f2bf(w[i]);
}

// ---------------- kernel 1: xwT[b][o][m*4+r] = bf16(x[b,m,:]@W[r][:,o]) ----
__global__ __launch_bounds__(512) void k1_xw(const float* __restrict__ x,
                                             const ushort* __restrict__ wT,
                                             ushort* __restrict__ xwT) {
  __shared__ char smem[65536];
  ushort* As = (ushort*)smem;           // [64 m][32 d]
  ushort* Bs = (ushort*)(smem + 4096);  // [4 r][128 o][32 d]
  const int t = threadIdx.x, l = t & 63, w = t >> 6;
  const int r = w >> 1, oh = w & 1;
  const int blk = blockIdx.x;
  const int b = blk >> 6, rest = blk & 63, mc = rest >> 1, ot = rest & 1;

  f32x4 acc[4][4] = {};
  const int arow = t >> 3, adc = (t & 7) << 2;
  const float* xg = x + ((size_t)(b * NN + mc * 64 + arow) * DIN + adc);

  for (int s = 0; s < 8; ++s) {
    const int d0 = s * 32;
    float4 xv = *(const float4*)(xg + d0);
    ushort4 a4;
    a4.x = f2bf(xv.x); a4.y = f2bf(xv.y); a4.z = f2bf(xv.z); a4.w = f2bf(xv.w);
    *(ushort4*)(As + arow * 32 + adc) = a4;
#pragma unroll
    for (int i = 0; i < 4; ++i) {
      int off = i * 4096 + t * 8;
      int rr = off >> 12, rem = off & 4095, o = rem >> 5, dd = rem & 31;
      const ushort* src = wT + ((size_t)(rr * DOUT + ot * 128 + o) * DIN + d0 + dd);
      gload_lds16(src, Bs + off);
    }
    __syncthreads();
    bf16x8 af[4];
#pragma unroll
    for (int fm = 0; fm < 4; ++fm)
      af[fm] = *(const bf16x8*)(As + (fm * 16 + (l & 15)) * 32 + (l >> 4) * 8);
#pragma unroll
    for (int fo = 0; fo < 4; ++fo) {
      bf16x8 bf = *(const bf16x8*)(Bs + (size_t)(r * 128 + oh * 64 + fo * 16 + (l & 15)) * 32 + (l >> 4) * 8);
#pragma unroll
      for (int fm = 0; fm < 4; ++fm)
        acc[fm][fo] = __builtin_amdgcn_mfma_f32_16x16x32_bf16(af[fm], bf, acc[fm][fo], 0, 0, 0);
    }
    __syncthreads();
  }
  ushort* Cs = (ushort*)smem;
#pragma unroll
  for (int fm = 0; fm < 4; ++fm)
#pragma unroll
    for (int fo = 0; fo < 4; ++fo)
#pragma unroll
      for (int j = 0; j < 4; ++j) {
        int o_loc = oh * 64 + fo * 16 + (l & 15);
        int ml = fm * 16 + (l >> 4) * 4 + j;
        Cs[o_loc * 256 + ml * 4 + r] = f2bf(acc[fm][fo][j]);
      }
  __syncthreads();
#pragma unroll
  for (int i = 0; i < 8; ++i) {
    int el = (i * 512 + t) * 8;
    int o_loc = el >> 8, kp = el & 255;
    *(uint4*)(xwT + (size_t)(b * DOUT + ot * 128 + o_loc) * KTOT + mc * 256 + kp) =
        *(const uint4*)(Cs + el);
  }
}

// ---------------- kernel 2: one-hot GEMM, A in registers, B via LDS -------
// grid 512 logical: b.nt.ks.ot, XCD-swizzled (ot-pairs co-XCD).
// 256 thr = 4 waves (2x2), wave 64x64, 4x4 frags 16x16x32, BK=64.
// A: built per-lane from rel int2 loads (one-hot, no LDS, no barrier dep).
// B: 3-buffer gload_lds (source pre-swizzled), depth-2 counted pipeline.
// Barrier: s_waitcnt vmcnt(12) lgkmcnt(0) + s_barrier — the newest 12 vm
// ops (B(s+2)x4 + rel(s+1)x8) stay in flight; B(s+1) retired. lgkmcnt(0)
// fences this wave's ds_reads of the buffer restaged next step (WAR).
__global__ __launch_bounds__(256, 2) void k2_main(const int* __restrict__ rel,
                                                  const ushort* __restrict__ xwT,
                                                  float* __restrict__ out,
                                                  float* __restrict__ part) {
  __shared__ char smem[49152];
  const int t = threadIdx.x, l = t & 63, w = t >> 6;
  const int wr = w >> 1, wc = w & 1;
  const int logical = (blockIdx.x & 7) * 64 + (blockIdx.x >> 3);
  const int b = logical >> 6;
  const int nt = (logical >> 2) & 15;
  const int ks = (logical >> 1) & 1;
  const int ot = logical & 1;

  f32x4 acc[4][4] = {};
  const int fr = l & 15, fq = l >> 4;
  const int rswz = (fr & 7) << 4;

  // per-lane rel pointer: row = nt*128 + wr*64 + fr (+ fm*16), col base fq*2
  const int* relp = rel + ((size_t)(b * NN + nt * 128 + wr * 64 + fr)) * NN +
                    ks * 1024 + fq * 2;

  const ushort* xwb = xwT + (size_t)(b * DOUT + ot * 128) * KTOT + ks * 4096;

  char* const Bb0 = smem;
  char* const Bb1 = smem + 16384;
  char* const Bb2 = smem + 32768;

  // B staging: thread t owns rows o=(t>>3)+32*i, source col pre-swizzled (#21)
  const int brow = t >> 3;
  const int kd = (((t & 7) ^ ((t >> 3) & 7)) << 3);  // elem offset, swz

  int2 rv0[8], rv1[8];  // rel prefetch; idx = fm*2 + kk; parity = step&1

#define STAGE_B(S, BBASE)                                                      \
  {                                                                            \
    _Pragma("unroll") for (int i = 0; i < 4; ++i)                              \
      gload_lds16(xwb + (size_t)(brow + 32 * i) * KTOT + (S) * 64 + kd,        \
                  (BBASE) + i * 4096 + t * 16);                                \
  }

#define RELLOAD(S, RV)                                                         \
  _Pragma("unroll") for (int ff = 0; ff < 8; ++ff) {                           \
    const int fm_ = ff >> 1, kk_ = ff & 1;                                     \
    RV[ff] = *(const int2*)(relp + (size_t)fm_ * 16 * NN + (S) * 16 + kk_ * 8);\
  }

#define BARV12()                                                               \
  asm volatile("s_waitcnt vmcnt(12) lgkmcnt(0)" ::: "memory");                 \
  __builtin_amdgcn_s_barrier();                                                \
  __builtin_amdgcn_sched_barrier(0);

#define BARV8()                                                                \
  asm volatile("s_waitcnt vmcnt(8) lgkmcnt(0)" ::: "memory");                  \
  __builtin_amdgcn_s_barrier();                                                \
  __builtin_amdgcn_sched_barrier(0);

#define MFMA_STEP(BC, RV)                                                      \
  __builtin_amdgcn_s_setprio(1);                                               \
  _Pragma("unroll") for (int kk = 0; kk < 2; ++kk) {                           \
    bf16x8 bfv[4];                                                             \
    const int colb = (kk * 64 + fq * 16) ^ rswz;                               \
    _Pragma("unroll") for (int fo = 0; fo < 4; ++fo)                           \
      bfv[fo] = *(const bf16x8*)((BC) + (wc * 64 + fo * 16 + fr) * 128 + colb);\
    _Pragma("unroll") for (int fm = 0; fm < 4; ++fm) {                         \
      bf16x8 af = onehot8(RV[fm * 2 + kk].x, RV[fm * 2 + kk].y);               \
      _Pragma("unroll") for (int fo = 0; fo < 4; ++fo)                         \
        acc[fm][fo] = __builtin_amdgcn_mfma_f32_16x16x32_bf16(                 \
            af, bfv[fo], acc[fm][fo], 0, 0, 0);                                \
    }                                                                          \
  }                                                                            \
  __builtin_amdgcn_s_setprio(0);

// body(S): stage B(S+2), prefetch rel(S+1)->rvQ, MFMA(S) from BCUR+rvP, bar
#define BODY(S, P, Q, BCUR, BSTG)                                              \
  {                                                                            \
    STAGE_B((S) + 2, BSTG);                                                    \
    RELLOAD((S) + 1, rv##Q);                                                   \
    MFMA_STEP(BCUR, rv##P);                                                    \
    BARV12();                                                                  \
  }

  // prologue: B(0),B(1) staged; rel(0) in regs; vmcnt(12) retires B(0)
  STAGE_B(0, Bb0);
  STAGE_B(1, Bb1);
  RELLOAD(0, rv0);
  BARV12();

  for (int s = 0; s < 60; s += 6) {
    BODY(s + 0, 0, 1, Bb0, Bb2);
    BODY(s + 1, 1, 0, Bb1, Bb0);
    BODY(s + 2, 0, 1, Bb2, Bb1);
    BODY(s + 3, 1, 0, Bb0, Bb2);
    BODY(s + 4, 0, 1, Bb1, Bb0);
    BODY(s + 5, 1, 0, Bb2, Bb1);
  }
  BODY(60, 0, 1, Bb0, Bb2);   // stages B(62)->Bb2, rel(61)->rv1
  BODY(61, 1, 0, Bb1, Bb0);   // stages B(63)->Bb0, rel(62)->rv0
  {  // s = 62: no stage; rel(63)->rv1; vmcnt(8) retires B(63)
    RELLOAD(63, rv1);
    MFMA_STEP(Bb2, rv0);
    BARV8();
  }
  {  // s = 63
    MFMA_STEP(Bb0, rv1);
  }

  float* dst = ks ? part : out;
#pragma unroll
  for (int fm = 0; fm < 4; ++fm)
#pragma unroll
    for (int fo = 0; fo < 4; ++fo) {
      int n = nt * 128 + wr * 64 + fm * 16 + fq * 4;
      int o = ot * 128 + wc * 64 + fo * 16 + fr;
#pragma unroll
      for (int j = 0; j < 4; ++j)
        dst[(size_t)(b * NN + n + j) * DOUT + o] = acc[fm][fo][j];
    }
#undef BODY
#undef MFMA_STEP
#undef BARV12
#undef BARV8
#undef RELLOAD
#undef STAGE_B
}

// ---------------- kernel 3: out = out(ks0) + part(ks1) + bias --------------
__global__ void k3_add(float* __restrict__ out, const float* __restrict__ part,
                       const float* __restrict__ bias) {
  int i = blockIdx.x * 256 + threadIdx.x;  // float4 index, 1048576 total
  float4 o = ((const float4*)out)[i];
  float4 p = ((const float4*)part)[i];
  float4 bv = ((const float4*)bias)[i & 63];
  float4 rr;
  rr.x = o.x + p.x + bv.x;
  rr.y = o.y + p.y + bv.y;
  rr.z = o.z + p.z + bv.z;
  rr.w = o.w + p.w + bv.w;
  ((float4*)out)[i] = rr;
}

extern "C" void kernel_launch(void* const* d_in, const int* in_sizes, int n_in,
                              void* d_out, int out_size, void* d_ws, size_t ws_size,
                              hipStream_t stream) {
  const float* x = (const float*)d_in[0];
  const int* rel = (const int*)d_in[2];
  const float* wgt = (const float*)d_in[3];
  const float* bias = (const float*)d_in[4];
  float* out = (float*)d_out;
  char* ws = (char*)d_ws;

  ushort* xwT = (ushort*)ws;                                 // 32 MiB
  float* part = (float*)(ws + XW_BYTES);                     // 16 MiB
  ushort* wT = (ushort*)(ws + XW_BYTES + PART_BYTES);        // 0.5 MiB

  k0_wT<<<1024, 256, 0, stream>>>(wgt, wT);
  k1_xw<<<512, 512, 0, stream>>>(x, wT, xwT);
  k2_main<<<512, 256, 0, stream>>>(rel, xwT, out, part);
  k3_add<<<4096, 256, 0, stream>>>(out, part, bias);
}

// Round 7
// 120.075 us; speedup vs baseline: 1.5749x; 1.5749x over previous
//
#include <hip/hip_runtime.h>
#include <hip/hip_bf16.h>
#include <stdint.h>

typedef uint32_t u32;
typedef uint64_t u64;
typedef __bf16 bf16x8 __attribute__((ext_vector_type(8)));
typedef float f32x4 __attribute__((ext_vector_type(4)));
typedef u32 u32x4 __attribute__((ext_vector_type(4)));

#define NB 8
#define NN 2048
#define DIN 256
#define DOUT 256
#define NR 4
#define KTOT (NN * NR)  // 8192

#define XW_BYTES   (NB * DOUT * KTOT * 2)          // 33,554,432
#define PART_BYTES (NB * NN * DOUT * 4)            // 16,777,216
#define WT_BYTES   (NR * DIN * DOUT * 2)           // 524,288
#define PART_F     (NB * NN * DOUT)                // 4,194,304 floats

__device__ __forceinline__ ushort f2bf(float f) {
  union { float f; u32 u; } c; c.f = f;
  return (ushort)((c.u + 0x7FFFu + ((c.u >> 16) & 1u)) >> 16);
}

__device__ __forceinline__ void gload_lds16(const void* g, void* l) {
  __builtin_amdgcn_global_load_lds(
      (const __attribute__((address_space(1))) u32*)g,
      (__attribute__((address_space(3))) u32*)l, 16, 0, 0);
}

// ---------------- kernel 0: wT[r][o][d] = bf16(w[r][d][o]) ----------------
__global__ void k0_wT(const float* __restrict__ w, ushort* __restrict__ wT) {
  int i = blockIdx.x * 256 + threadIdx.x;   // 262144 total
  int o = i & 255, d = (i >> 8) & 255, r = i >> 16;
  wT[(r * DOUT + o) * DIN + d] = f2bf(w[i]);
}

// ---------------- kernel 1: xwT[b][o][m*4+r] = bf16(x[b,m,:]@W[r][:,o]) ----
__global__ __launch_bounds__(512) void k1_xw(const float* __restrict__ x,
                                             const ushort* __restrict__ wT,
                                             ushort* __restrict__ xwT) {
  __shared__ char smem[65536];
  ushort* As = (ushort*)smem;           // [64 m][32 d]
  ushort* Bs = (ushort*)(smem + 4096);  // [4 r][128 o][32 d]
  const int t = threadIdx.x, l = t & 63, w = t >> 6;
  const int r = w >> 1, oh = w & 1;
  const int blk = blockIdx.x;
  const int b = blk >> 6, rest = blk & 63, mc = rest >> 1, ot = rest & 1;

  f32x4 acc[4][4] = {};
  const int arow = t >> 3, adc = (t & 7) << 2;
  const float* xg = x + ((size_t)(b * NN + mc * 64 + arow) * DIN + adc);

  for (int s = 0; s < 8; ++s) {
    const int d0 = s * 32;
    float4 xv = *(const float4*)(xg + d0);
    ushort4 a4;
    a4.x = f2bf(xv.x); a4.y = f2bf(xv.y); a4.z = f2bf(xv.z); a4.w = f2bf(xv.w);
    *(ushort4*)(As + arow * 32 + adc) = a4;
#pragma unroll
    for (int i = 0; i < 4; ++i) {
      int off = i * 4096 + t * 8;
      int rr = off >> 12, rem = off & 4095, o = rem >> 5, dd = rem & 31;
      const ushort* src = wT + ((size_t)(rr * DOUT + ot * 128 + o) * DIN + d0 + dd);
      gload_lds16(src, Bs + off);
    }
    __syncthreads();
    bf16x8 af[4];
#pragma unroll
    for (int fm = 0; fm < 4; ++fm)
      af[fm] = *(const bf16x8*)(As + (fm * 16 + (l & 15)) * 32 + (l >> 4) * 8);
#pragma unroll
    for (int fo = 0; fo < 4; ++fo) {
      bf16x8 bf = *(const bf16x8*)(Bs + (size_t)(r * 128 + oh * 64 + fo * 16 + (l & 15)) * 32 + (l >> 4) * 8);
#pragma unroll
      for (int fm = 0; fm < 4; ++fm)
        acc[fm][fo] = __builtin_amdgcn_mfma_f32_16x16x32_bf16(af[fm], bf, acc[fm][fo], 0, 0, 0);
    }
    __syncthreads();
  }
  ushort* Cs = (ushort*)smem;
#pragma unroll
  for (int fm = 0; fm < 4; ++fm)
#pragma unroll
    for (int fo = 0; fo < 4; ++fo)
#pragma unroll
      for (int j = 0; j < 4; ++j) {
        int o_loc = oh * 64 + fo * 16 + (l & 15);
        int ml = fm * 16 + (l >> 4) * 4 + j;
        Cs[o_loc * 256 + ml * 4 + r] = f2bf(acc[fm][fo][j]);
      }
  __syncthreads();
#pragma unroll
  for (int i = 0; i < 8; ++i) {
    int el = (i * 512 + t) * 8;
    int o_loc = el >> 8, kp = el & 255;
    *(uint4*)(xwT + (size_t)(b * DOUT + ot * 128 + o_loc) * KTOT + mc * 256 + kp) =
        *(const uint4*)(Cs + el);
  }
}

// ============= kernel 2 (BIG): 256x256 tile, 8-phase-style schedule =======
// grid 256 logical: b(8).nt(8).ks(4); XCD-swizzled so each XCD owns one b.
// 512 thr = 8 waves (2M x 4N), wave 128x64, 8x4 frags of 16x16x32, BK=64.
// LDS 128KB: A[256][64] dbuf (one-hot expand, XOR-swz write) +
//            B[256][64] dbuf (gload_lds, pre-swizzled source).
// 4 phases/step: {ds_read subtile; stage; bar; lgkm0; schedbar; prio1;
// 16 MFMA; prio0; bar}. rel loads in P2 (after all 4 glds, order pinned by
// the two asm memory-clobbers) so end-of-step vmcnt(2) keeps only rel(s+2)
// in flight and guarantees B(s+1) resident.
__global__ __launch_bounds__(512, 2) void k2_big(const int* __restrict__ rel,
                                                 const ushort* __restrict__ xwT,
                                                 float* __restrict__ out,
                                                 float* __restrict__ part) {
  __shared__ char smem[131072];
  const int t = threadIdx.x, l = t & 63, w = t >> 6;
  const int wm = w >> 2, wn = w & 3;
  const int logical = (blockIdx.x & 7) * 32 + (blockIdx.x >> 3);
  const int b = logical >> 5;
  const int nt = (logical >> 2) & 7;
  const int ks = logical & 3;

  f32x4 acc[8][4] = {};
  const int fr = l & 15, fq = l >> 4;
  const int rswz = (fr & 7) << 4;

  char* const Ab0 = smem;
  char* const Ab1 = smem + 32768;
  char* const Bb0 = smem + 65536;
  char* const Bb1 = smem + 98304;

  // rel: thread t owns row t>>1 (0..255), half = t&1 (8 ints)
  const int arow = t >> 1, half = t & 1;
  const int aswz = (arow & 7) << 4;
  const int* relg = rel + ((size_t)(b * NN + nt * 256 + arow)) * NN + ks * 512 + half * 8;

  // B staging: thread t owns rows o=(t>>3)+64*i, 16B chunk (t&7), src preswz
  const int brow = t >> 3;
  const int kd = (((t & 7) ^ ((t >> 3) & 7)) << 3);  // element offset
  const ushort* xwb = xwT + (size_t)b * DOUT * KTOT + ks * 2048;

  int4 rs0a, rs0b, rs1a, rs1b;  // rel(k) lives in set k&1

#define GLD2(S, BB, I0, I1)                                                    \
  gload_lds16(xwb + (size_t)(brow + 64 * I0) * KTOT + (S) * 64 + kd,           \
              (BB) + I0 * 8192 + t * 16);                                      \
  gload_lds16(xwb + (size_t)(brow + 64 * I1) * KTOT + (S) * 64 + kd,           \
              (BB) + I1 * 8192 + t * 16);

#define RELLOAD(S, RA, RB)                                                     \
  RA = *(const int4*)(relg + (S) * 16);                                        \
  RB = *(const int4*)(relg + (S) * 16 + 4);

#define EXPAND_A(ABASE, V0, V1)                                                \
  {                                                                            \
    char* rowp = (ABASE) + arow * 128;                                         \
    int vv[8] = {V0.x, V0.y, V0.z, V0.w, V1.x, V1.y, V1.z, V1.w};              \
    _Pragma("unroll") for (int p = 0; p < 4; ++p) {                            \
      int va = vv[2 * p], vb = vv[2 * p + 1];                                  \
      u32 sa = ((u32)(va - 1) & 3u) * 16u;                                     \
      u32 sb = ((u32)(vb - 1) & 3u) * 16u;                                     \
      u64 ha = va ? (0x3F80ull << sa) : 0ull;                                  \
      u64 hb = vb ? (0x3F80ull << sb) : 0ull;                                  \
      u32x4 e = {(u32)ha, (u32)(ha >> 32), (u32)hb, (u32)(hb >> 32)};          \
      *(u32x4*)(rowp + ((half * 64 + p * 16) ^ aswz)) = e;                     \
    }                                                                          \
  }

#define RD_B(BFV, BB)                                                          \
  _Pragma("unroll") for (int kk = 0; kk < 2; ++kk)                             \
    _Pragma("unroll") for (int fo = 0; fo < 4; ++fo)                           \
      BFV[kk * 4 + fo] = *(const bf16x8*)((BB) + (wn * 64 + fo * 16 + fr) * 128 + \
                                          ((kk * 64 + fq * 16) ^ rswz));

#define RD_A2(A0, A1, A2, A3, AB, FMa, FMb)                                    \
  A0 = *(const bf16x8*)((AB) + (wm * 128 + FMa * 16 + fr) * 128 + ((fq * 16) ^ rswz)); \
  A1 = *(const bf16x8*)((AB) + (wm * 128 + FMa * 16 + fr) * 128 + ((64 + fq * 16) ^ rswz)); \
  A2 = *(const bf16x8*)((AB) + (wm * 128 + FMb * 16 + fr) * 128 + ((fq * 16) ^ rswz)); \
  A3 = *(const bf16x8*)((AB) + (wm * 128 + FMb * 16 + fr) * 128 + ((64 + fq * 16) ^ rswz));

#define MFMA_Q(A0, A1, A2, A3, BFV, FMa, FMb)                                  \
  _Pragma("unroll") for (int fo = 0; fo < 4; ++fo)                             \
    acc[FMa][fo] = __builtin_amdgcn_mfma_f32_16x16x32_bf16(A0, BFV[fo], acc[FMa][fo], 0, 0, 0); \
  _Pragma("unroll") for (int fo = 0; fo < 4; ++fo)                             \
    acc[FMa][fo] = __builtin_amdgcn_mfma_f32_16x16x32_bf16(A1, BFV[4 + fo], acc[FMa][fo], 0, 0, 0); \
  _Pragma("unroll") for (int fo = 0; fo < 4; ++fo)                             \
    acc[FMb][fo] = __builtin_amdgcn_mfma_f32_16x16x32_bf16(A2, BFV[fo], acc[FMb][fo], 0, 0, 0); \
  _Pragma("unroll") for (int fo = 0; fo < 4; ++fo)                             \
    acc[FMb][fo] = __builtin_amdgcn_mfma_f32_16x16x32_bf16(A3, BFV[4 + fo], acc[FMb][fo], 0, 0, 0);

#define PH_MID()                                                               \
  __builtin_amdgcn_s_barrier();                                                \
  asm volatile("s_waitcnt lgkmcnt(0)" ::: "memory");                           \
  __builtin_amdgcn_sched_barrier(0);                                           \
  __builtin_amdgcn_s_setprio(1)

#define PH_END()                                                               \
  __builtin_amdgcn_s_setprio(0);                                               \
  __builtin_amdgcn_s_barrier()

#define STEP(S, P, Q, STG, REL, EXP, VMS)                                      \
  {                                                                            \
    bf16x8 bfv[8], af0, af1, af2, af3;                                         \
    /* P0 */                                                                   \
    RD_B(bfv, Bb##P);                                                          \
    RD_A2(af0, af1, af2, af3, Ab##P, 0, 1);                                    \
    if (STG) { GLD2((S) + 1, Bb##Q, 0, 1); }                                   \
    PH_MID();                                                                  \
    MFMA_Q(af0, af1, af2, af3, bfv, 0, 1);                                     \
    PH_END();                                                                  \
    /* P1 */                                                                   \
    RD_A2(af0, af1, af2, af3, Ab##P, 2, 3);                                    \
    if (STG) { GLD2((S) + 1, Bb##Q, 2, 3); }                                   \
    PH_MID();                                                                  \
    MFMA_Q(af0, af1, af2, af3, bfv, 2, 3);                                     \
    PH_END();                                                                  \
    /* P2: expand A(S+1) from rel set Q; load rel(S+2) into set P (after all glds) */ \
    RD_A2(af0, af1, af2, af3, Ab##P, 4, 5);                                    \
    if (EXP) { EXPAND_A(Ab##Q, rs##Q##a, rs##Q##b); }                          \
    if (REL) { RELLOAD((S) + 2, rs##P##a, rs##P##b); }                         \
    PH_MID();                                                                  \
    MFMA_Q(af0, af1, af2, af3, bfv, 4, 5);                                     \
    PH_END();                                                                  \
    /* P3 */                                                                   \
    RD_A2(af0, af1, af2, af3, Ab##P, 6, 7);                                    \
    PH_MID();                                                                  \
    MFMA_Q(af0, af1, af2, af3, bfv, 6, 7);                                     \
    __builtin_amdgcn_s_setprio(0);                                             \
    asm volatile("s_waitcnt vmcnt(" VMS ")" ::: "memory");                     \
    __builtin_amdgcn_s_barrier();                                              \
    __builtin_amdgcn_sched_barrier(0);                                         \
  }

  // prologue: stage B(0); rel(0),rel(1); expand A(0)
  GLD2(0, Bb0, 0, 1);
  GLD2(0, Bb0, 2, 3);
  RELLOAD(0, rs0a, rs0b);
  RELLOAD(1, rs1a, rs1b);
  EXPAND_A(Ab0, rs0a, rs0b);  // compiler waits rel(0), draining B(0) glds too
  asm volatile("s_waitcnt lgkmcnt(0)" ::: "memory");
  __builtin_amdgcn_s_barrier();
  __builtin_amdgcn_sched_barrier(0);

  for (int s = 0; s < 30; s += 2) {
    STEP(s, 0, 1, 1, 1, 1, "2");
    STEP(s + 1, 1, 0, 1, 1, 1, "2");
  }
  STEP(30, 0, 1, 1, 0, 1, "0");   // stages B(31); expands A(31) from rel(31)
  STEP(31, 1, 0, 0, 0, 0, "63");  // final compute, no staging

  float* dst = (ks == 0) ? out : part + (size_t)(ks - 1) * PART_F;
#pragma unroll
  for (int fm = 0; fm < 8; ++fm)
#pragma unroll
    for (int fo = 0; fo < 4; ++fo) {
      int n = nt * 256 + wm * 128 + fm * 16 + fq * 4;
      int o = wn * 64 + fo * 16 + fr;
#pragma unroll
      for (int j = 0; j < 4; ++j)
        dst[(size_t)(b * NN + n + j) * DOUT + o] = acc[fm][fo][j];
    }
#undef STEP
#undef PH_END
#undef PH_MID
#undef MFMA_Q
#undef RD_A2
#undef RD_B
#undef EXPAND_A
#undef RELLOAD
#undef GLD2
}

// ---------------- kernel 3 (BIG): out += part0+part1+part2 + bias ----------
__global__ void k3_big(float* __restrict__ out, const float* __restrict__ part,
                       const float* __restrict__ bias) {
  int i = blockIdx.x * 256 + threadIdx.x;  // float4 index, 1048576 total
  const float4* p = (const float4*)part;
  float4 o = ((const float4*)out)[i];
  float4 a = p[i];
  float4 c = p[i + (PART_F >> 2)];
  float4 d = p[i + (PART_F >> 1)];
  float4 bv = ((const float4*)bias)[i & 63];
  float4 rr;
  rr.x = o.x + a.x + c.x + d.x + bv.x;
  rr.y = o.y + a.y + c.y + d.y + bv.y;
  rr.z = o.z + a.z + c.z + d.z + bv.z;
  rr.w = o.w + a.w + c.w + d.w + bv.w;
  ((float4*)out)[i] = rr;
}

// ============= fallback path: exact R4 kernels (proven, 48.5MB ws) ========
__global__ __launch_bounds__(256, 2) void k2_r4(const int* __restrict__ rel,
                                                const ushort* __restrict__ xwT,
                                                float* __restrict__ out,
                                                float* __restrict__ part) {
  __shared__ char smem[81920];
  const int t = threadIdx.x, l = t & 63, w = t >> 6;
  const int wr = w >> 1, wc = w & 1;
  const int logical = (blockIdx.x & 7) * 64 + (blockIdx.x >> 3);
  const int b = logical >> 6;
  const int nt = (logical >> 2) & 15;
  const int ks = (logical >> 1) & 1;
  const int ot = logical & 1;

  f32x4 acc[4][4] = {};
  const int arow = t >> 1, half = t & 1;
  const int* relg = rel + ((size_t)(b * NN + nt * 128 + arow) * NN + ks * 1024 + half * 8);
  const ushort* xwb = xwT + (size_t)(b * DOUT + ot * 128) * KTOT + ks * 4096;

  char* const Ab0 = smem;
  char* const Ab1 = smem + 16384;
  char* const Bb0 = smem + 32768;
  char* const Bb1 = smem + 49152;
  char* const Bb2 = smem + 65536;

  const int brow = t >> 3;
  const int kd = (((t & 7) ^ ((t >> 3) & 7)) << 3);
  const int aswz = (arow & 7) << 4;
  const int fr = l & 15, fq = l >> 4;
  const int rswz = (fr & 7) << 4;

  int4 rsA0, rsB0, rsA1, rsB1;

#define STAGE_B(S, BBASE)                                                      \
  {                                                                            \
    _Pragma("unroll") for (int i = 0; i < 4; ++i)                              \
      gload_lds16(xwb + (size_t)(brow + 32 * i) * KTOT + (S) * 64 + kd,        \
                  (BBASE) + i * 4096 + t * 16);                                \
  }
#define RELLOAD(S, RA, RB)                                                     \
  RA = *(const int4*)(relg + (S) * 16);                                        \
  RB = *(const int4*)(relg + (S) * 16 + 4);
#define EXPAND_A(ABASE, V0, V1)                                                \
  {                                                                            \
    char* rowp = (ABASE) + arow * 128;                                         \
    int vv[8] = {V0.x, V0.y, V0.z, V0.w, V1.x, V1.y, V1.z, V1.w};              \
    _Pragma("unroll") for (int p = 0; p < 4; ++p) {                            \
      int va = vv[2 * p], vb = vv[2 * p + 1];                                  \
      u32 sa = ((u32)(va - 1) & 3u) * 16u;                                     \
      u32 sb = ((u32)(vb - 1) & 3u) * 16u;                                     \
      u64 ha = va ? (0x3F80ull << sa) : 0ull;                                  \
      u64 hb = vb ? (0x3F80ull << sb) : 0ull;                                  \
      u32x4 e = {(u32)ha, (u32)(ha >> 32), (u32)hb, (u32)(hb >> 32)};          \
      *(u32x4*)(rowp + ((half * 64 + p * 16) ^ aswz)) = e;                     \
    }                                                                          \
  }
#define BARV6()                                                                \
  asm volatile("s_waitcnt vmcnt(6) lgkmcnt(0)" ::: "memory");                  \
  __builtin_amdgcn_s_barrier();                                                \
  __builtin_amdgcn_sched_barrier(0);
#define BARV0()                                                                \
  asm volatile("s_waitcnt vmcnt(0) lgkmcnt(0)" ::: "memory");                  \
  __builtin_amdgcn_s_barrier();                                                \
  __builtin_amdgcn_sched_barrier(0);
#define MFMA_STEP(AC, BC)                                                      \
  __builtin_amdgcn_s_setprio(1);                                               \
  _Pragma("unroll") for (int kk = 0; kk < 2; ++kk) {                           \
    bf16x8 af[4], bfv[4];                                                      \
    const int colb = (kk * 64 + fq * 16) ^ rswz;                               \
    _Pragma("unroll") for (int fm = 0; fm < 4; ++fm)                           \
      af[fm] = *(const bf16x8*)((AC) + (wr * 64 + fm * 16 + fr) * 128 + colb); \
    _Pragma("unroll") for (int fo = 0; fo < 4; ++fo)                           \
      bfv[fo] = *(const bf16x8*)((BC) + (wc * 64 + fo * 16 + fr) * 128 + colb);\
    _Pragma("unroll") for (int fm = 0; fm < 4; ++fm)                           \
      _Pragma("unroll") for (int fo = 0; fo < 4; ++fo)                         \
        acc[fm][fo] = __builtin_amdgcn_mfma_f32_16x16x32_bf16(                 \
            af[fm], bfv[fo], acc[fm][fo], 0, 0, 0);                            \
  }                                                                            \
  __builtin_amdgcn_s_setprio(0);
#define BODY(S, ACUR, BCUR, ANXT, RLA, RLB, RCA, RCB, BSTG)                    \
  {                                                                            \
    STAGE_B((S) + 2, BSTG);                                                    \
    RELLOAD((S) + 2, RLA, RLB);                                                \
    MFMA_STEP(ACUR, BCUR);                                                     \
    EXPAND_A(ANXT, RCA, RCB);                                                  \
    BARV6();                                                                   \
  }

  STAGE_B(0, Bb0);
  RELLOAD(0, rsA0, rsB0);
  STAGE_B(1, Bb1);
  RELLOAD(1, rsA1, rsB1);
  EXPAND_A(Ab0, rsA0, rsB0);
  BARV6();

  for (int s = 0; s < 60; s += 6) {
    BODY(s + 0, Ab0, Bb0, Ab1, rsA0, rsB0, rsA1, rsB1, Bb2);
    BODY(s + 1, Ab1, Bb1, Ab0, rsA1, rsB1, rsA0, rsB0, Bb0);
    BODY(s + 2, Ab0, Bb2, Ab1, rsA0, rsB0, rsA1, rsB1, Bb1);
    BODY(s + 3, Ab1, Bb0, Ab0, rsA1, rsB1, rsA0, rsB0, Bb2);
    BODY(s + 4, Ab0, Bb1, Ab1, rsA0, rsB0, rsA1, rsB1, Bb0);
    BODY(s + 5, Ab1, Bb2, Ab0, rsA1, rsB1, rsA0, rsB0, Bb1);
  }
  BODY(60, Ab0, Bb0, Ab1, rsA0, rsB0, rsA1, rsB1, Bb2);
  BODY(61, Ab1, Bb1, Ab0, rsA1, rsB1, rsA0, rsB0, Bb0);
  {
    MFMA_STEP(Ab0, Bb2);
    EXPAND_A(Ab1, rsA1, rsB1);
    BARV0();
  }
  {
    MFMA_STEP(Ab1, Bb0);
  }

  float* dst = ks ? part : out;
#pragma unroll
  for (int fm = 0; fm < 4; ++fm)
#pragma unroll
    for (int fo = 0; fo < 4; ++fo) {
      int n = nt * 128 + wr * 64 + fm * 16 + fq * 4;
      int o = ot * 128 + wc * 64 + fo * 16 + fr;
#pragma unroll
      for (int j = 0; j < 4; ++j)
        dst[(size_t)(b * NN + n + j) * DOUT + o] = acc[fm][fo][j];
    }
#undef BODY
#undef MFMA_STEP
#undef BARV6
#undef BARV0
#undef EXPAND_A
#undef RELLOAD
#undef STAGE_B
}

__global__ void k3_r4(float* __restrict__ out, const float* __restrict__ part,
                      const float* __restrict__ bias) {
  int i = blockIdx.x * 256 + threadIdx.x;
  float4 o = ((const float4*)out)[i];
  float4 p = ((const float4*)part)[i];
  float4 bv = ((const float4*)bias)[i & 63];
  float4 rr;
  rr.x = o.x + p.x + bv.x;
  rr.y = o.y + p.y + bv.y;
  rr.z = o.z + p.z + bv.z;
  rr.w = o.w + p.w + bv.w;
  ((float4*)out)[i] = rr;
}

extern "C" void kernel_launch(void* const* d_in, const int* in_sizes, int n_in,
                              void* d_out, int out_size, void* d_ws, size_t ws_size,
                              hipStream_t stream) {
  const float* x = (const float*)d_in[0];
  const int* rel = (const int*)d_in[2];
  const float* wgt = (const float*)d_in[3];
  const float* bias = (const float*)d_in[4];
  float* out = (float*)d_out;
  char* ws = (char*)d_ws;

  const size_t need_big = (size_t)XW_BYTES + 3ull * PART_BYTES + WT_BYTES;
  if (ws_size >= need_big) {
    ushort* xwT = (ushort*)ws;
    float* part = (float*)(ws + XW_BYTES);
    ushort* wT = (ushort*)(ws + XW_BYTES + 3ull * PART_BYTES);
    k0_wT<<<1024, 256, 0, stream>>>(wgt, wT);
    k1_xw<<<512, 512, 0, stream>>>(x, wT, xwT);
    k2_big<<<256, 512, 0, stream>>>(rel, xwT, out, part);
    k3_big<<<4096, 256, 0, stream>>>(out, part, bias);
  } else {
    ushort* xwT = (ushort*)ws;
    float* part = (float*)(ws + XW_BYTES);
    ushort* wT = (ushort*)(ws + XW_BYTES + PART_BYTES);
    k0_wT<<<1024, 256, 0, stream>>>(wgt, wT);
    k1_xw<<<512, 512, 0, stream>>>(x, wT, xwT);
    k2_r4<<<512, 256, 0, stream>>>(rel, xwT, out, part);
    k3_r4<<<4096, 256, 0, stream>>>(out, part, bias);
  }
}

// Round 8
// 110.293 us; speedup vs baseline: 1.7146x; 1.0887x over previous
//
#include <hip/hip_runtime.h>
#include <hip/hip_bf16.h>
#include <stdint.h>

typedef uint32_t u32;
typedef uint64_t u64;
typedef __bf16 bf16x8 __attribute__((ext_vector_type(8)));
typedef float f32x4 __attribute__((ext_vector_type(4)));
typedef u32 u32x4 __attribute__((ext_vector_type(4)));

#define NB 8
#define NN 2048
#define DIN 256
#define DOUT 256
#define NR 4
#define KTOT (NN * NR)  // 8192

#define XW_BYTES   (NB * DOUT * KTOT * 2)          // 33,554,432
#define PART_BYTES (NB * NN * DOUT * 4)            // 16,777,216 (f32, fallback)
#define WT_BYTES   (NR * DIN * DOUT * 2)           // 524,288
#define PART_ELEMS (NB * NN * DOUT)                // 4,194,304

__device__ __forceinline__ ushort f2bf(float f) {
  union { float f; u32 u; } c; c.f = f;
  return (ushort)((c.u + 0x7FFFu + ((c.u >> 16) & 1u)) >> 16);
}

__device__ __forceinline__ float bf2f(ushort u) {
  union { u32 i; float f; } c; c.i = ((u32)u) << 16; return c.f;
}

__device__ __forceinline__ void gload_lds16(const void* g, void* l) {
  __builtin_amdgcn_global_load_lds(
      (const __attribute__((address_space(1))) u32*)g,
      (__attribute__((address_space(3))) u32*)l, 16, 0, 0);
}

// ---------------- kernel 0: wT[r][o][d] = bf16(w[r][d][o]) ----------------
__global__ void k0_wT(const float* __restrict__ w, ushort* __restrict__ wT) {
  int i = blockIdx.x * 256 + threadIdx.x;   // 262144 total
  int o = i & 255, d = (i >> 8) & 255, r = i >> 16;
  wT[(r * DOUT + o) * DIN + d] = f2bf(w[i]);
}

// ---------------- kernel 1: xwT[b][o][m*4+r] = bf16(x[b,m,:]@W[r][:,o]) ----
__global__ __launch_bounds__(512) void k1_xw(const float* __restrict__ x,
                                             const ushort* __restrict__ wT,
                                             ushort* __restrict__ xwT) {
  __shared__ char smem[65536];
  ushort* As = (ushort*)smem;           // [64 m][32 d]
  ushort* Bs = (ushort*)(smem + 4096);  // [4 r][128 o][32 d]
  const int t = threadIdx.x, l = t & 63, w = t >> 6;
  const int r = w >> 1, oh = w & 1;
  const int blk = blockIdx.x;
  const int b = blk >> 6, rest = blk & 63, mc = rest >> 1, ot = rest & 1;

  f32x4 acc[4][4] = {};
  const int arow = t >> 3, adc = (t & 7) << 2;
  const float* xg = x + ((size_t)(b * NN + mc * 64 + arow) * DIN + adc);

  for (int s = 0; s < 8; ++s) {
    const int d0 = s * 32;
    float4 xv = *(const float4*)(xg + d0);
    ushort4 a4;
    a4.x = f2bf(xv.x); a4.y = f2bf(xv.y); a4.z = f2bf(xv.z); a4.w = f2bf(xv.w);
    *(ushort4*)(As + arow * 32 + adc) = a4;
#pragma unroll
    for (int i = 0; i < 4; ++i) {
      int off = i * 4096 + t * 8;
      int rr = off >> 12, rem = off & 4095, o = rem >> 5, dd = rem & 31;
      const ushort* src = wT + ((size_t)(rr * DOUT + ot * 128 + o) * DIN + d0 + dd);
      gload_lds16(src, Bs + off);
    }
    __syncthreads();
    bf16x8 af[4];
#pragma unroll
    for (int fm = 0; fm < 4; ++fm)
      af[fm] = *(const bf16x8*)(As + (fm * 16 + (l & 15)) * 32 + (l >> 4) * 8);
#pragma unroll
    for (int fo = 0; fo < 4; ++fo) {
      bf16x8 bf = *(const bf16x8*)(Bs + (size_t)(r * 128 + oh * 64 + fo * 16 + (l & 15)) * 32 + (l >> 4) * 8);
#pragma unroll
      for (int fm = 0; fm < 4; ++fm)
        acc[fm][fo] = __builtin_amdgcn_mfma_f32_16x16x32_bf16(af[fm], bf, acc[fm][fo], 0, 0, 0);
    }
    __syncthreads();
  }
  ushort* Cs = (ushort*)smem;
#pragma unroll
  for (int fm = 0; fm < 4; ++fm)
#pragma unroll
    for (int fo = 0; fo < 4; ++fo)
#pragma unroll
      for (int j = 0; j < 4; ++j) {
        int o_loc = oh * 64 + fo * 16 + (l & 15);
        int ml = fm * 16 + (l >> 4) * 4 + j;
        Cs[o_loc * 256 + ml * 4 + r] = f2bf(acc[fm][fo][j]);
      }
  __syncthreads();
#pragma unroll
  for (int i = 0; i < 8; ++i) {
    int el = (i * 512 + t) * 8;
    int o_loc = el >> 8, kp = el & 255;
    *(uint4*)(xwT + (size_t)(b * DOUT + ot * 128 + o_loc) * KTOT + mc * 256 + kp) =
        *(const uint4*)(Cs + el);
  }
}

// ============= kernel 2 v2: 256x256 tile, ONE barrier per K-step ==========
// grid 256 logical: b(8).nt(8).ks(4); XCD-swizzled so each XCD owns one b.
// 512 thr = 8 waves (2M x 4N), wave 128x64, 8x4 frags 16x16x32, BK=64.
// LDS 128KB: A[256][64] dbuf (one-hot expand) + B[256][64] dbuf (gload_lds).
// Per step: issue ALL ds_reads phase-ahead into rotating reg sets, glds for
// B(s+1), rel(s+2) (order pinned after glds); 4 MFMA quads (kk x fm-quad)
// paced by compiler's fine-grained lgkmcnt; EXPAND_A mid-step (overlaps
// other waves' MFMA); single end fence: vmcnt(2) lgkmcnt(0) + s_barrier —
// rel(s+2) stays in flight across the barrier (T4).
__global__ __launch_bounds__(512, 2) void k2_v2(const int* __restrict__ rel,
                                                const ushort* __restrict__ xwT,
                                                ushort* __restrict__ partb) {
  __shared__ char smem[131072];
  const int t = threadIdx.x, l = t & 63, w = t >> 6;
  const int wm = w >> 2, wn = w & 3;
  const int logical = (blockIdx.x & 7) * 32 + (blockIdx.x >> 3);
  const int b = logical >> 5;
  const int nt = (logical >> 2) & 7;
  const int ks = logical & 3;

  f32x4 acc[8][4] = {};
  const int fr = l & 15, fq = l >> 4;
  const int rswz = (fr & 7) << 4;

  char* const Ab0 = smem;
  char* const Ab1 = smem + 32768;
  char* const Bb0 = smem + 65536;
  char* const Bb1 = smem + 98304;

  const int arow = t >> 1, half = t & 1;
  const int aswz = (arow & 7) << 4;
  const int* relg = rel + ((size_t)(b * NN + nt * 256 + arow)) * NN + ks * 512 + half * 8;

  const int brow = t >> 3;
  const int kd = (((t & 7) ^ ((t >> 3) & 7)) << 3);  // element offset, preswz
  const ushort* xwb = xwT + (size_t)b * DOUT * KTOT + ks * 2048;

  int4 rs0a, rs0b, rs1a, rs1b;  // rel(k) lives in set k&1

#define GLD_ALL(S, BB)                                                         \
  {                                                                            \
    _Pragma("unroll") for (int i = 0; i < 4; ++i)                              \
      gload_lds16(xwb + (size_t)(brow + 64 * i) * KTOT + (S) * 64 + kd,        \
                  (BB) + i * 8192 + t * 16);                                   \
  }

#define RELLOAD(S, RA, RB)                                                     \
  RA = *(const int4*)(relg + (S) * 16);                                        \
  RB = *(const int4*)(relg + (S) * 16 + 4);

#define EXPAND_A(ABASE, V0, V1)                                                \
  {                                                                            \
    char* rowp = (ABASE) + arow * 128;                                         \
    int vv[8] = {V0.x, V0.y, V0.z, V0.w, V1.x, V1.y, V1.z, V1.w};              \
    _Pragma("unroll") for (int p = 0; p < 4; ++p) {                            \
      int va = vv[2 * p], vb = vv[2 * p + 1];                                  \
      u32 sa = ((u32)(va - 1) & 3u) * 16u;                                     \
      u32 sb = ((u32)(vb - 1) & 3u) * 16u;                                     \
      u64 ha = va ? (0x3F80ull << sa) : 0ull;                                  \
      u64 hb = vb ? (0x3F80ull << sb) : 0ull;                                  \
      u32x4 e = {(u32)ha, (u32)(ha >> 32), (u32)hb, (u32)(hb >> 32)};          \
      *(u32x4*)(rowp + ((half * 64 + p * 16) ^ aswz)) = e;                     \
    }                                                                          \
  }

#define RDB(BV, BB, KK)                                                        \
  _Pragma("unroll") for (int fo = 0; fo < 4; ++fo)                             \
    BV[fo] = *(const bf16x8*)((BB) + (wn * 64 + fo * 16 + fr) * 128 +          \
                              (((KK) * 64 + fq * 16) ^ rswz));

#define RDA(AV, AB, FM0, KK)                                                   \
  _Pragma("unroll") for (int i = 0; i < 4; ++i)                                \
    AV[i] = *(const bf16x8*)((AB) + (wm * 128 + ((FM0) + i) * 16 + fr) * 128 + \
                             (((KK) * 64 + fq * 16) ^ rswz));

#define MFMA4(FM0, AV, BV)                                                     \
  __builtin_amdgcn_s_setprio(1);                                               \
  _Pragma("unroll") for (int i = 0; i < 4; ++i)                                \
    _Pragma("unroll") for (int fo = 0; fo < 4; ++fo)                           \
      acc[(FM0) + i][fo] = __builtin_amdgcn_mfma_f32_16x16x32_bf16(            \
          AV[i], BV[fo], acc[(FM0) + i][fo], 0, 0, 0);                         \
  __builtin_amdgcn_s_setprio(0);

#define ENDFENCE(VMS)                                                          \
  asm volatile("s_waitcnt vmcnt(" VMS ") lgkmcnt(0)" ::: "memory");            \
  __builtin_amdgcn_s_barrier();                                                \
  __builtin_amdgcn_sched_barrier(0);

// One K-step: P = S&1 buffers current, Q staged/expanded.
#define STEP(S, P, Q, STG, REL, EXP, VMS)                                      \
  {                                                                            \
    bf16x8 b0[4], b1[4], aA[4], aB[4], aC[4], aD[4];                           \
    RDB(b0, Bb##P, 0);                                                         \
    RDA(aA, Ab##P, 0, 0);                                                      \
    if (STG) { GLD_ALL((S) + 1, Bb##Q); }                                      \
    __builtin_amdgcn_sched_barrier(0);                                         \
    if (REL) { RELLOAD((S) + 2, rs##P##a, rs##P##b); }                         \
    RDA(aB, Ab##P, 4, 0);                                                      \
    MFMA4(0, aA, b0);                                                          \
    RDA(aC, Ab##P, 0, 1);                                                      \
    if (EXP) { EXPAND_A(Ab##Q, rs##Q##a, rs##Q##b); }                          \
    MFMA4(4, aB, b0);                                                          \
    RDB(b1, Bb##P, 1);                                                         \
    RDA(aD, Ab##P, 4, 1);                                                      \
    MFMA4(0, aC, b1);                                                          \
    MFMA4(4, aD, b1);                                                          \
    ENDFENCE(VMS);                                                             \
  }

  // prologue: B(0) staged; rel(0),rel(1) loaded; A(0) expanded
  GLD_ALL(0, Bb0);
  __builtin_amdgcn_sched_barrier(0);
  RELLOAD(0, rs0a, rs0b);
  RELLOAD(1, rs1a, rs1b);
  EXPAND_A(Ab0, rs0a, rs0b);  // compiler auto-waits rel(0)
  ENDFENCE("4");              // retire the 4 glds; rel(1) may stay in flight

  for (int s = 0; s < 30; s += 2) {
    STEP(s, 0, 1, 1, 1, 1, "2");
    STEP(s + 1, 1, 0, 1, 1, 1, "2");
  }
  STEP(30, 0, 1, 1, 0, 1, "0");  // stages B(31); expands A(31); drain all
  {  // s = 31: final compute, no staging, no trailing fence
    bf16x8 b0[4], b1[4], aA[4], aB[4], aC[4], aD[4];
    RDB(b0, Bb1, 0);
    RDA(aA, Ab1, 0, 0);
    RDA(aB, Ab1, 4, 0);
    MFMA4(0, aA, b0);
    RDA(aC, Ab1, 0, 1);
    MFMA4(4, aB, b0);
    RDB(b1, Bb1, 1);
    RDA(aD, Ab1, 4, 1);
    MFMA4(0, aC, b1);
    MFMA4(4, aD, b1);
  }

  ushort* dst = partb + (size_t)ks * PART_ELEMS;
#pragma unroll
  for (int fm = 0; fm < 8; ++fm)
#pragma unroll
    for (int fo = 0; fo < 4; ++fo) {
      int n = nt * 256 + wm * 128 + fm * 16 + fq * 4;
      int o = wn * 64 + fo * 16 + fr;
#pragma unroll
      for (int j = 0; j < 4; ++j)
        dst[(size_t)(b * NN + n + j) * DOUT + o] = f2bf(acc[fm][fo][j]);
    }
#undef STEP
#undef ENDFENCE
#undef MFMA4
#undef RDA
#undef RDB
#undef EXPAND_A
#undef RELLOAD
#undef GLD_ALL
}

// ---------------- kernel 3 v2: out = sum of 4 bf16 partials + bias --------
__global__ void k3_sum(float* __restrict__ out, const ushort* __restrict__ partb,
                       const float* __restrict__ bias) {
  int i = blockIdx.x * 256 + threadIdx.x;  // float4-group, 1048576 total
  float4 s = ((const float4*)bias)[i & 63];
#pragma unroll
  for (int p = 0; p < 4; ++p) {
    ushort4 v = ((const ushort4*)(partb + (size_t)p * PART_ELEMS))[i];
    s.x += bf2f(v.x); s.y += bf2f(v.y); s.z += bf2f(v.z); s.w += bf2f(v.w);
  }
  ((float4*)out)[i] = s;
}

// ============= fallback path: exact R4 kernels (proven, 50.9MB ws) ========
__global__ __launch_bounds__(256, 2) void k2_r4(const int* __restrict__ rel,
                                                const ushort* __restrict__ xwT,
                                                float* __restrict__ out,
                                                float* __restrict__ part) {
  __shared__ char smem[81920];
  const int t = threadIdx.x, l = t & 63, w = t >> 6;
  const int wr = w >> 1, wc = w & 1;
  const int logical = (blockIdx.x & 7) * 64 + (blockIdx.x >> 3);
  const int b = logical >> 6;
  const int nt = (logical >> 2) & 15;
  const int ks = (logical >> 1) & 1;
  const int ot = logical & 1;

  f32x4 acc[4][4] = {};
  const int arow = t >> 1, half = t & 1;
  const int* relg = rel + ((size_t)(b * NN + nt * 128 + arow) * NN + ks * 1024 + half * 8);
  const ushort* xwb = xwT + (size_t)(b * DOUT + ot * 128) * KTOT + ks * 4096;

  char* const Ab0 = smem;
  char* const Ab1 = smem + 16384;
  char* const Bb0 = smem + 32768;
  char* const Bb1 = smem + 49152;
  char* const Bb2 = smem + 65536;

  const int brow = t >> 3;
  const int kd = (((t & 7) ^ ((t >> 3) & 7)) << 3);
  const int aswz = (arow & 7) << 4;
  const int fr = l & 15, fq = l >> 4;
  const int rswz = (fr & 7) << 4;

  int4 rsA0, rsB0, rsA1, rsB1;

#define STAGE_B(S, BBASE)                                                      \
  {                                                                            \
    _Pragma("unroll") for (int i = 0; i < 4; ++i)                              \
      gload_lds16(xwb + (size_t)(brow + 32 * i) * KTOT + (S) * 64 + kd,        \
                  (BBASE) + i * 4096 + t * 16);                                \
  }
#define RELLOAD(S, RA, RB)                                                     \
  RA = *(const int4*)(relg + (S) * 16);                                        \
  RB = *(const int4*)(relg + (S) * 16 + 4);
#define EXPAND_A(ABASE, V0, V1)                                                \
  {                                                                            \
    char* rowp = (ABASE) + arow * 128;                                         \
    int vv[8] = {V0.x, V0.y, V0.z, V0.w, V1.x, V1.y, V1.z, V1.w};              \
    _Pragma("unroll") for (int p = 0; p < 4; ++p) {                            \
      int va = vv[2 * p], vb = vv[2 * p + 1];                                  \
      u32 sa = ((u32)(va - 1) & 3u) * 16u;                                     \
      u32 sb = ((u32)(vb - 1) & 3u) * 16u;                                     \
      u64 ha = va ? (0x3F80ull << sa) : 0ull;                                  \
      u64 hb = vb ? (0x3F80ull << sb) : 0ull;                                  \
      u32x4 e = {(u32)ha, (u32)(ha >> 32), (u32)hb, (u32)(hb >> 32)};          \
      *(u32x4*)(rowp + ((half * 64 + p * 16) ^ aswz)) = e;                     \
    }                                                                          \
  }
#define BARV6()                                                                \
  asm volatile("s_waitcnt vmcnt(6) lgkmcnt(0)" ::: "memory");                  \
  __builtin_amdgcn_s_barrier();                                                \
  __builtin_amdgcn_sched_barrier(0);
#define BARV0()                                                                \
  asm volatile("s_waitcnt vmcnt(0) lgkmcnt(0)" ::: "memory");                  \
  __builtin_amdgcn_s_barrier();                                                \
  __builtin_amdgcn_sched_barrier(0);
#define MFMA_STEP(AC, BC)                                                      \
  __builtin_amdgcn_s_setprio(1);                                               \
  _Pragma("unroll") for (int kk = 0; kk < 2; ++kk) {                           \
    bf16x8 af[4], bfv[4];                                                      \
    const int colb = (kk * 64 + fq * 16) ^ rswz;                               \
    _Pragma("unroll") for (int fm = 0; fm < 4; ++fm)                           \
      af[fm] = *(const bf16x8*)((AC) + (wr * 64 + fm * 16 + fr) * 128 + colb); \
    _Pragma("unroll") for (int fo = 0; fo < 4; ++fo)                           \
      bfv[fo] = *(const bf16x8*)((BC) + (wc * 64 + fo * 16 + fr) * 128 + colb);\
    _Pragma("unroll") for (int fm = 0; fm < 4; ++fm)                           \
      _Pragma("unroll") for (int fo = 0; fo < 4; ++fo)                         \
        acc[fm][fo] = __builtin_amdgcn_mfma_f32_16x16x32_bf16(                 \
            af[fm], bfv[fo], acc[fm][fo], 0, 0, 0);                            \
  }                                                                            \
  __builtin_amdgcn_s_setprio(0);
#define BODY(S, ACUR, BCUR, ANXT, RLA, RLB, RCA, RCB, BSTG)                    \
  {                                                                            \
    STAGE_B((S) + 2, BSTG);                                                    \
    RELLOAD((S) + 2, RLA, RLB);                                                \
    MFMA_STEP(ACUR, BCUR);                                                     \
    EXPAND_A(ANXT, RCA, RCB);                                                  \
    BARV6();                                                                   \
  }

  STAGE_B(0, Bb0);
  RELLOAD(0, rsA0, rsB0);
  STAGE_B(1, Bb1);
  RELLOAD(1, rsA1, rsB1);
  EXPAND_A(Ab0, rsA0, rsB0);
  BARV6();

  for (int s = 0; s < 60; s += 6) {
    BODY(s + 0, Ab0, Bb0, Ab1, rsA0, rsB0, rsA1, rsB1, Bb2);
    BODY(s + 1, Ab1, Bb1, Ab0, rsA1, rsB1, rsA0, rsB0, Bb0);
    BODY(s + 2, Ab0, Bb2, Ab1, rsA0, rsB0, rsA1, rsB1, Bb1);
    BODY(s + 3, Ab1, Bb0, Ab0, rsA1, rsB1, rsA0, rsB0, Bb2);
    BODY(s + 4, Ab0, Bb1, Ab1, rsA0, rsB0, rsA1, rsB1, Bb0);
    BODY(s + 5, Ab1, Bb2, Ab0, rsA1, rsB1, rsA0, rsB0, Bb1);
  }
  BODY(60, Ab0, Bb0, Ab1, rsA0, rsB0, rsA1, rsB1, Bb2);
  BODY(61, Ab1, Bb1, Ab0, rsA1, rsB1, rsA0, rsB0, Bb0);
  {
    MFMA_STEP(Ab0, Bb2);
    EXPAND_A(Ab1, rsA1, rsB1);
    BARV0();
  }
  {
    MFMA_STEP(Ab1, Bb0);
  }

  float* dst = ks ? part : out;
#pragma unroll
  for (int fm = 0; fm < 4; ++fm)
#pragma unroll
    for (int fo = 0; fo < 4; ++fo) {
      int n = nt * 128 + wr * 64 + fm * 16 + fq * 4;
      int o = ot * 128 + wc * 64 + fo * 16 + fr;
#pragma unroll
      for (int j = 0; j < 4; ++j)
        dst[(size_t)(b * NN + n + j) * DOUT + o] = acc[fm][fo][j];
    }
#undef BODY
#undef MFMA_STEP
#undef BARV6
#undef BARV0
#undef EXPAND_A
#undef RELLOAD
#undef STAGE_B
}

__global__ void k3_r4(float* __restrict__ out, const float* __restrict__ part,
                      const float* __restrict__ bias) {
  int i = blockIdx.x * 256 + threadIdx.x;
  float4 o = ((const float4*)out)[i];
  float4 p = ((const float4*)part)[i];
  float4 bv = ((const float4*)bias)[i & 63];
  float4 rr;
  rr.x = o.x + p.x + bv.x;
  rr.y = o.y + p.y + bv.y;
  rr.z = o.z + p.z + bv.z;
  rr.w = o.w + p.w + bv.w;
  ((float4*)out)[i] = rr;
}

extern "C" void kernel_launch(void* const* d_in, const int* in_sizes, int n_in,
                              void* d_out, int out_size, void* d_ws, size_t ws_size,
                              hipStream_t stream) {
  const float* x = (const float*)d_in[0];
  const int* rel = (const int*)d_in[2];
  const float* wgt = (const float*)d_in[3];
  const float* bias = (const float*)d_in[4];
  float* out = (float*)d_out;
  char* ws = (char*)d_ws;

  const size_t partb_bytes = (size_t)PART_ELEMS * 2 * 4;  // 4 bf16 partials
  const size_t need_big = (size_t)XW_BYTES + partb_bytes + WT_BYTES;
  if (ws_size >= need_big) {
    ushort* xwT = (ushort*)ws;
    ushort* partb = (ushort*)(ws + XW_BYTES);
    ushort* wT = (ushort*)(ws + XW_BYTES + partb_bytes);
    k0_wT<<<1024, 256, 0, stream>>>(wgt, wT);
    k1_xw<<<512, 512, 0, stream>>>(x, wT, xwT);
    k2_v2<<<256, 512, 0, stream>>>(rel, xwT, partb);
    k3_sum<<<4096, 256, 0, stream>>>(out, partb, bias);
  } else {
    ushort* xwT = (ushort*)ws;
    float* part = (float*)(ws + XW_BYTES);
    ushort* wT = (ushort*)(ws + XW_BYTES + PART_BYTES);
    k0_wT<<<1024, 256, 0, stream>>>(wgt, wT);
    k1_xw<<<512, 512, 0, stream>>>(x, wT, xwT);
    k2_r4<<<512, 256, 0, stream>>>(rel, xwT, out, part);
    k3_r4<<<4096, 256, 0, stream>>>(out, part, bias);
  }
}